// Round 3
// baseline (133.030 us; speedup 1.0000x reference)
//
#include <hip/hip_runtime.h>

// out[b,i,j,d] = sum_{k<c} A[b,i,k,d] * B[b,k,j,d]   for i,j < c, else 0
// A: (256,64,64,32) f32, strides: b:131072, i:2048, k:32, d:1
// B: (256,64,64,32) f32, strides: b:131072, k:2048, j:32, d:1
//
// v3: float4 over d; thread = (j-pair, d-quad) = 256 thr covering 64j x 32d;
// i-chunk 4 (grid = 16 x 256 = 4096 blocks) for finer load balance.
// Per k-iter/thread: 6 x 16B coalesced loads + 32 FMA (was 12 x 4B + 32 FMA).

#define BATCH 256
#define NN 64
#define ND 32
#define BSTRIDE (NN * NN * ND)   // 131072 floats
#define RSTRIDE (NN * ND)        // 2048 floats
#define ICHUNK 4

__global__ __launch_bounds__(256, 4) void mp_kernel(
    const float* __restrict__ A,
    const float* __restrict__ B,
    const int* __restrict__ counts,
    float* __restrict__ out)
{
    const int b  = blockIdx.x & (BATCH - 1);
    const int ic = blockIdx.x >> 8;          // 0..15
    const int i0 = ic * ICHUNK;
    const int c  = counts[b];
    const int tid = (int)threadIdx.x;
    const int d4 = tid & 7;                  // d quad: d = d4*4 .. +3
    const int jp = tid >> 3;                 // 0..31, pair of j's
    const int j0 = jp << 1;

    const size_t base = (size_t)b * BSTRIDE;
    float* __restrict__ Ob = out + base + (size_t)i0 * RSTRIDE + (size_t)j0 * ND + d4 * 4;

    // fast path: whole i-chunk invalid -> zero-fill and retire
    if (i0 >= c) {
        const float4 z = make_float4(0.f, 0.f, 0.f, 0.f);
        #pragma unroll
        for (int ii = 0; ii < ICHUNK; ++ii)
            #pragma unroll
            for (int jj = 0; jj < 2; ++jj)
                *reinterpret_cast<float4*>(Ob + (size_t)ii * RSTRIDE + jj * ND) = z;
        return;
    }

    // float4 views; element indices are in float4 units (float idx / 4)
    const float4* __restrict__ A4 =
        reinterpret_cast<const float4*>(A + base + (size_t)i0 * RSTRIDE) + d4; // + ii*512 + k*8
    const float4* __restrict__ B4 =
        reinterpret_cast<const float4*>(B + base + (size_t)j0 * ND) + d4;      // + k*512 + jj*8

    float acc[ICHUNK][2][4];
    #pragma unroll
    for (int ii = 0; ii < ICHUNK; ++ii)
        #pragma unroll
        for (int jj = 0; jj < 2; ++jj)
            #pragma unroll
            for (int dd = 0; dd < 4; ++dd)
                acc[ii][jj][dd] = 0.0f;

    // wave w covers j in [16w, 16w+16); skip compute if entirely invalid
    const bool waveActive = (((tid >> 6) << 4) < c);

    if (waveActive) {
        #pragma unroll 2
        for (int k = 0; k < c; ++k) {
            float4 bv0 = B4[(size_t)k * (RSTRIDE / 4)];
            float4 bv1 = B4[(size_t)k * (RSTRIDE / 4) + (ND / 4)];
            float4 av[ICHUNK];
            #pragma unroll
            for (int ii = 0; ii < ICHUNK; ++ii)
                av[ii] = A4[(size_t)ii * (RSTRIDE / 4) + (size_t)k * (ND / 4)];
            #pragma unroll
            for (int ii = 0; ii < ICHUNK; ++ii) {
                acc[ii][0][0] = fmaf(av[ii].x, bv0.x, acc[ii][0][0]);
                acc[ii][0][1] = fmaf(av[ii].y, bv0.y, acc[ii][0][1]);
                acc[ii][0][2] = fmaf(av[ii].z, bv0.z, acc[ii][0][2]);
                acc[ii][0][3] = fmaf(av[ii].w, bv0.w, acc[ii][0][3]);
                acc[ii][1][0] = fmaf(av[ii].x, bv1.x, acc[ii][1][0]);
                acc[ii][1][1] = fmaf(av[ii].y, bv1.y, acc[ii][1][1]);
                acc[ii][1][2] = fmaf(av[ii].z, bv1.z, acc[ii][1][2]);
                acc[ii][1][3] = fmaf(av[ii].w, bv1.w, acc[ii][1][3]);
            }
        }
    }

    // masked store (output poisoned before timing -> write everything)
    #pragma unroll
    for (int ii = 0; ii < ICHUNK; ++ii) {
        const bool iv = (i0 + ii) < c;
        #pragma unroll
        for (int jj = 0; jj < 2; ++jj) {
            const bool v = iv && ((j0 + jj) < c);
            const float4 o = v ? make_float4(acc[ii][jj][0], acc[ii][jj][1],
                                             acc[ii][jj][2], acc[ii][jj][3])
                               : make_float4(0.f, 0.f, 0.f, 0.f);
            *reinterpret_cast<float4*>(Ob + (size_t)ii * RSTRIDE + jj * ND) = o;
        }
    }
}

extern "C" void kernel_launch(void* const* d_in, const int* in_sizes, int n_in,
                              void* d_out, int out_size, void* d_ws, size_t ws_size,
                              hipStream_t stream)
{
    const float* A      = (const float*)d_in[0];
    const float* B      = (const float*)d_in[1];
    const int*   counts = (const int*)d_in[2];
    float* out = (float*)d_out;

    mp_kernel<<<dim3(BATCH * (NN / ICHUNK)), dim3(256), 0, stream>>>(A, B, counts, out);
}